// Round 3
// baseline (1578.107 us; speedup 1.0000x reference)
//
#include <hip/hip_runtime.h>
#include <hip/hip_bf16.h>
#include <stdint.h>

typedef __hip_bfloat16 bf16_t;
typedef __attribute__((ext_vector_type(4))) float f32x4;
typedef __attribute__((ext_vector_type(8))) short s16x8;

#define UNITS 768
#define NCOLS 3072        // 4*UNITS (gates, reordered)
#define NPRED 96
#define MROWS 2048

__device__ __forceinline__ float sigf(float x) {
    return __builtin_amdgcn_rcpf(1.f + __expf(-x));
}
__device__ __forceinline__ float tanh_fast(float x) {
    return 1.f - 2.f * __builtin_amdgcn_rcpf(1.f + __expf(2.f * x));
}

// ---------------- prep kernels (once per launch, off critical path) ---------------

// B0T[c][k] = W_ih[g*768+u][k], c-reordered (linear), K=96
__global__ void prep_b0(const float* __restrict__ W_ih, bf16_t* __restrict__ B0T) {
    int idx = blockIdx.x * 256 + threadIdx.x;
    if (idx >= NCOLS * 96) return;
    int c = idx / 96, k = idx % 96;
    int u = ((c >> 6) << 4) + (c & 15);
    int g = (c >> 4) & 3;
    B0T[idx] = (bf16_t)W_ih[(g * UNITS + u) * 96 + k];
}

// x0 in A-fragment layout: elem((mf*3+kf)*512 + l*8 + j) = x[mf*16+(l&15)][kf*32+(l>>4)*8+j]
__global__ void prep_x0(const float* __restrict__ inputs, bf16_t* __restrict__ x0) {
    int idx = blockIdx.x * 256 + threadIdx.x; // 2048*96 = 196608 exactly
    int j = idx & 7;
    int l = (idx >> 3) & 63;
    int fg = idx >> 9;          // mf*3 + kf
    int kf = fg % 3;
    int mf = fg / 3;
    int m = mf * 16 + (l & 15);
    int k = kf * 32 + (l >> 4) * 8 + j;
    x0[idx] = (bf16_t)inputs[(m * 24 + 23) * 96 + k];
}

__global__ void prep_bias(const float* __restrict__ b_ih, const float* __restrict__ b_hh,
                          const float* __restrict__ W_ih, const float* __restrict__ b_d,
                          float* __restrict__ b0_r, float* __restrict__ beff_r) {
    int c = blockIdx.x * 256 + threadIdx.x;
    if (c >= NCOLS) return;
    int u = ((c >> 6) << 4) + (c & 15);
    int g = (c >> 4) & 3;
    int r = g * UNITS + u;
    float v = b_ih[r] + b_hh[r];
    float acc = 0.f;
    for (int j = 0; j < 96; ++j) acc += W_ih[r * 96 + j] * b_d[j];
    b0_r[c] = v;
    beff_r[c] = v + acc;
}

// BeffT[c][k] = W_hh[r(c)][k] + sum_j W_ih[r(c)][j]*W_d[j][k]   (c<3072, LDS-tiled)
__global__ void prep_beff2(const float* __restrict__ W_hh, const float* __restrict__ W_ih,
                           const float* __restrict__ W_d, bf16_t* __restrict__ BeffT) {
    __shared__ float sWih[64][96];
    __shared__ float sWd[96][64];
    const int c0 = blockIdx.x * 64, k0 = blockIdx.y * 64;
    const int tid = threadIdx.x;
    for (int i = tid; i < 64 * 96; i += 256) {
        int cc = i / 96, j = i % 96;
        int c = c0 + cc;
        int u = ((c >> 6) << 4) + (c & 15);
        int g = (c >> 4) & 3;
        sWih[cc][j] = W_ih[(g * UNITS + u) * 96 + j];
    }
    for (int i = tid; i < 96 * 64; i += 256) {
        int j = i / 64, kk = i % 64;
        sWd[j][kk] = W_d[j * UNITS + k0 + kk];
    }
    __syncthreads();
    const int kk = tid & 63;
    const int cc0 = (tid >> 6) * 16;
    for (int cc = cc0; cc < cc0 + 16; ++cc) {
        float acc = 0.f;
#pragma unroll 12
        for (int j = 0; j < 96; ++j) acc += sWih[cc][j] * sWd[j][kk];
        int c = c0 + cc;
        int u = ((c >> 6) << 4) + (c & 15);
        int g = (c >> 4) & 3;
        int r = g * UNITS + u;
        BeffT[(size_t)c * UNITS + k0 + kk] = (bf16_t)(W_hh[(size_t)r * UNITS + k0 + kk] + acc);
    }
}

// rows 3072..3199 of BeffT: W_d rows then zero pad
__global__ void prep_wdt(const float* __restrict__ W_d, bf16_t* __restrict__ BeffT) {
    int idx = blockIdx.x * 256 + threadIdx.x; // 128*768
    int c = idx / UNITS, k = idx % UNITS;
    float v = (c < NPRED) ? W_d[c * UNITS + k] : 0.f;
    BeffT[(size_t)(NCOLS + c) * UNITS + k] = (bf16_t)v;
}

// swizzle linear [c][K] (c pre-reordered) -> B-fragment order:
// elem((((nw*Knk + kf)*4 + f)*64 + l)*8 + j) = src[c][k],
//   c = (nw>>1)*128 + (nw&1)*64 + f*16 + (l&15),  k = kf*32 + (l>>4)*8 + j
__global__ void prep_swz(const bf16_t* __restrict__ src, bf16_t* __restrict__ dst,
                         int Knk, int K, int total) {
    int idx = blockIdx.x * 256 + threadIdx.x;
    if (idx >= total) return;
    int j = idx & 7;
    int l = (idx >> 3) & 63;
    int fg = idx >> 9;
    int f = fg & 3;
    int rest = fg >> 2;
    int kf = rest % Knk;
    int nw = rest / Knk;
    int c = (nw >> 1) * 128 + (nw & 1) * 64 + f * 16 + (l & 15);
    int k = kf * 32 + (l >> 4) * 8 + j;
    dst[idx] = src[(size_t)c * K + k];
}

__global__ void zero_ctr(int* __restrict__ c) {
    int i = blockIdx.x * 256 + threadIdx.x;
    if (i < 512) c[i] = 0;   // 8 groups x 64 steps
}

// ---------------- persistent kernel: all 64 steps in one launch ---------------
// Geometry (round-3): 8 groups x 256 rows; each group = 25 blocks of 128 cols.
// Block = 256 rows x 128 cols, 8 waves (4 row-slices x 2 col-halves), 512 threads.
// With bid&7 XCD round-robin, each group lives on ONE XCD: barrier traffic and
// h exchange stay XCD-local (heuristic only; protocol is mapping-independent).
// B: 96 of 128 cols LDS-resident (144 KB, frags 0..2 of both 64-col stripes);
// 4th frag (cols 48-63 of each half) streamed from global, uniform for all waves.
// c-state in registers. 4-slot register pipeline (3-deep prefetch) to cover
// post-invalidate L3 refill latency (~600 cyc).
// Barrier protocol identical to round 2 (proven): release add (wbl2) by
// producers, relaxed poll, single acquire load (buffer_inv) on exit.
__global__ __launch_bounds__(512, 2)
void lstm_persist(const bf16_t* __restrict__ x0s,
                  const bf16_t* __restrict__ B0s,
                  const bf16_t* __restrict__ Bs,
                  const float* __restrict__ b0r,
                  const float* __restrict__ beffr,
                  const float* __restrict__ b_d,
                  bf16_t* __restrict__ h0,
                  bf16_t* __restrict__ h1,
                  float* __restrict__ out,
                  int* __restrict__ ctr)
{
    __shared__ __align__(16) bf16_t smem[24 * 6 * 512];   // 73728 elems = 144 KB

    const int tid = threadIdx.x;
    const int wv   = tid >> 6;
    const int lane = tid & 63;
    const int wr = wv >> 1, wc = wv & 1;   // row-slice 0..3, col-half 0..1
    const int l15 = lane & 15, l4 = lane >> 4;

    const int bid  = blockIdx.x;        // 200 blocks
    const int grp  = bid & 7;           // row group 0..7 (256 rows) -> one XCD
    const int tile = bid >> 3;          // 0..24 : 128-col tile
    const bool is_pred = (tile == 24);

    // this wave's global B stripe (64-col stripe 2*tile+wc); frag 3 streamed
    const bf16_t* Bg = Bs + (size_t)(2 * tile + wc) * 49152;

    // ---- stage B frags 0..2 of stripes 2t,2t+1 into LDS (144 KB) ----
    // dst[(kf*6 + wcs*3 + f)*64 + l] (f32x4 units) = stripe(2t+wcs) frag f
    {
        const f32x4* s0 = (const f32x4*)(Bs + (size_t)(2 * tile) * 49152);
        const f32x4* s1 = (const f32x4*)(Bs + (size_t)(2 * tile + 1) * 49152);
        f32x4* dst = (f32x4*)smem;
        for (int i = tid; i < 9216; i += 512) {
            int l  = i & 63;
            int ff = (i >> 6) % 6;          // 0..5
            int kf = i / 384;
            int f  = (ff >= 3) ? ff - 3 : ff;
            const f32x4* src = (ff >= 3) ? s1 : s0;
            dst[i] = src[(kf * 4 + f) * 64 + l];
        }
    }

    // ---- per-thread constants ----
    int aoffh[4], aoff0[4];
#pragma unroll
    for (int i = 0; i < 4; ++i) {
        int mf = grp * 16 + wr * 4 + i;     // 16-row fragment index (0..127)
        aoffh[i] = (mf * 24) * 512 + lane * 8;
        aoff0[i] = (mf * 3) * 512 + lane * 8;
    }
    int boff0[4];
#pragma unroll
    for (int f = 0; f < 4; ++f)
        boff0[f] = (((2 * tile + wc) * 12 + f) * 64 + lane) * 8;  // B0s (step 0)

    const int ldsb = wc * 1536 + lane * 8;   // LDS B base (elems); +kt*3072 +j*512
    const int bgof = 1536 + lane * 8;        // global frag 3 base; +kt*2048

    float bi0[4], biS[4];
    if (!is_pred) {
#pragma unroll
        for (int f = 0; f < 4; ++f) {
            int idx = tile * 128 + wc * 64 + f * 16 + l15;
            bi0[f] = b0r[idx];
            biS[f] = beffr[idx];
        }
    } else {
#pragma unroll
        for (int f = 0; f < 4; ++f) {
            int j = wc * 64 + f * 16 + l15;
            biS[f] = (j < NPRED) ? b_d[j] : 0.f;
            bi0[f] = 0.f;
        }
    }

    const int kq = wc * 2 + (l15 >> 3);
    const int jj = l15 & 7;

    f32x4 creg[4];          // persistent cell state for this thread's tile
#pragma unroll
    for (int i = 0; i < 4; ++i) creg[i] = f32x4{0.f, 0.f, 0.f, 0.f};

    int* cbase = ctr + grp * 64;

    f32x4 acc[4][4];

#define ZACC() do {                                                                  \
        _Pragma("unroll") for (int _i = 0; _i < 4; ++_i)                             \
        _Pragma("unroll") for (int _j = 0; _j < 4; ++_j)                             \
            acc[_i][_j] = f32x4{0.f, 0.f, 0.f, 0.f};                                 \
    } while (0)

#define LOADK_H(BUF, KT) do {                                                        \
        _Pragma("unroll")                                                            \
        for (int _i = 0; _i < 4; ++_i)                                               \
            afr[BUF][_i] = *(const s16x8*)(hA + aoffh[_i] + (size_t)(KT) * 512);     \
        _Pragma("unroll")                                                            \
        for (int _f = 0; _f < 3; ++_f)                                               \
            bfr[BUF][_f] = *(const s16x8*)(smem + ldsb + (KT) * 3072 + _f * 512);    \
        bfr[BUF][3] = *(const s16x8*)(Bg + bgof + (size_t)(KT) * 2048);              \
    } while (0)

#define LOADK_0(BUF, KT) do {                                                        \
        _Pragma("unroll")                                                            \
        for (int _i = 0; _i < 4; ++_i)                                               \
            afr[BUF][_i] = *(const s16x8*)(x0s + aoff0[_i] + (size_t)(KT) * 512);    \
        _Pragma("unroll")                                                            \
        for (int _f = 0; _f < 4; ++_f)                                               \
            bfr[BUF][_f] = *(const s16x8*)(B0s + boff0[_f] + (size_t)(KT) * 2048);   \
    } while (0)

#define MF(BUF) do {                                                                 \
        _Pragma("unroll")                                                            \
        for (int _i = 0; _i < 4; ++_i)                                               \
            _Pragma("unroll")                                                        \
            for (int _j = 0; _j < 4; ++_j)                                           \
                acc[_i][_j] = __builtin_amdgcn_mfma_f32_16x16x32_bf16(               \
                    afr[BUF][_i], bfr[BUF][_j], acc[_i][_j], 0, 0, 0);               \
    } while (0)

// 4-slot register pipeline, 3-deep prefetch (covers ~240cy x 2 waves/SIMD)
#define RUN4(NK, LOADK) do {                                                         \
        s16x8 afr[4][4], bfr[4][4];                                                  \
        LOADK(0, 0);                                                                 \
        if (1 < (NK)) LOADK(1, 1);                                                   \
        if (2 < (NK)) LOADK(2, 2);                                                   \
        for (int _kt = 0; _kt < (NK); _kt += 4) {                                    \
            if (_kt + 3 < (NK)) LOADK(3, _kt + 3);                                   \
            MF(0);                                                                   \
            if (_kt + 4 < (NK)) LOADK(0, _kt + 4);                                   \
            if (_kt + 1 < (NK)) MF(1);                                               \
            if (_kt + 5 < (NK)) LOADK(1, _kt + 5);                                   \
            if (_kt + 2 < (NK)) MF(2);                                               \
            if (_kt + 6 < (NK)) LOADK(2, _kt + 6);                                   \
            if (_kt + 3 < (NK)) MF(3);                                               \
        }                                                                            \
    } while (0)

#define GATE_EPI(HW, BI) do {                                                        \
        _Pragma("unroll")                                                            \
        for (int _i = 0; _i < 4; ++_i) {                                             \
            const int _mf = grp * 16 + wr * 4 + _i;                                  \
            bf16_t* _hb = (HW) + (size_t)(_mf * 24 + tile) * 512;                    \
            _Pragma("unroll")                                                        \
            for (int _r = 0; _r < 4; ++_r) {                                         \
                float _gi = acc[_i][0][_r] + (BI)[0];                                \
                float _gf = acc[_i][1][_r] + (BI)[1];                                \
                float _gg = acc[_i][2][_r] + (BI)[2];                                \
                float _go = acc[_i][3][_r] + (BI)[3];                                \
                float _si = sigf(_gi);                                               \
                float _sf = sigf(_gf);                                               \
                float _tg = tanh_fast(_gg);                                          \
                float _so = sigf(_go);                                               \
                float _cn = _sf * creg[_i][_r] + _si * _tg;                          \
                creg[_i][_r] = _cn;                                                  \
                int _lp = (l4 * 4 + _r) | (kq << 4);                                 \
                _hb[_lp * 8 + jj] = (bf16_t)(_so * tanh_fast(_cn));                  \
            }                                                                        \
        }                                                                            \
    } while (0)

#define PRED_EPI(TCOL) do {                                                          \
        _Pragma("unroll")                                                            \
        for (int _f = 0; _f < 4; ++_f) {                                             \
            int _j = wc * 64 + _f * 16 + l15;                                        \
            if (_j < NPRED) {                                                        \
                _Pragma("unroll")                                                    \
                for (int _i = 0; _i < 4; ++_i)                                       \
                    _Pragma("unroll")                                                \
                    for (int _r = 0; _r < 4; ++_r) {                                 \
                        int _row = grp * 256 + wr * 64 + _i * 16 + l4 * 4 + _r;      \
                        out[((size_t)_row * 64 + (TCOL)) * NPRED + _j] =             \
                            acc[_i][_f][_r] + biS[_f];                               \
                    }                                                                \
            }                                                                        \
        }                                                                            \
    } while (0)

    // Round-2-proven protocol: one wbl2 (release add, producers) + one inv
    // (final acquire load) per block per step; RELAXED polls in between.
    auto barrier_step = [&](int s) {
        __syncthreads();                       // all waves' h stores vmcnt-retired
        if (tid == 0) {
            if (is_pred) {
                __hip_atomic_fetch_add(cbase + s, 1, __ATOMIC_RELAXED,
                                       __HIP_MEMORY_SCOPE_AGENT);
            } else {
                __hip_atomic_fetch_add(cbase + s, 1, __ATOMIC_RELEASE,
                                       __HIP_MEMORY_SCOPE_AGENT);
            }
            int it = 0;
            while (__hip_atomic_load(cbase + s, __ATOMIC_RELAXED,
                                     __HIP_MEMORY_SCOPE_AGENT) < 25) {
                __builtin_amdgcn_s_sleep(4);
                if (++it > (1 << 23)) break;   // failsafe: wrong answer > hang
            }
            (void)__hip_atomic_load(cbase + s, __ATOMIC_ACQUIRE,
                                    __HIP_MEMORY_SCOPE_AGENT);
        }
        __syncthreads();
    };

    // ---- step 0: gates from x0 (Knk=3), c=h=0; pred idle ----
    if (!is_pred) {
        ZACC();
        RUN4(3, LOADK_0);
        GATE_EPI(h1, bi0);
    }
    barrier_step(0);

    // ---- steps 1..63 ----
    for (int s = 1; s < 64; ++s) {
        const bf16_t* hA = (s & 1) ? h1 : h0;
        ZACC();
        RUN4(24, LOADK_H);
        if (!is_pred) {
            bf16_t* hW = ((s + 1) & 1) ? h1 : h0;
            GATE_EPI(hW, biS);
        } else {
            PRED_EPI(s - 1);
        }
        barrier_step(s);
    }

    // ---- step 64: final prediction from h_64 (in h0) ----
    if (is_pred) {
        const bf16_t* hA = h0;
        ZACC();
        RUN4(24, LOADK_H);
        PRED_EPI(63);
    }

#undef ZACC
#undef LOADK_H
#undef LOADK_0
#undef MF
#undef RUN4
#undef GATE_EPI
#undef PRED_EPI
}

extern "C" void kernel_launch(void* const* d_in, const int* in_sizes, int n_in,
                              void* d_out, int out_size, void* d_ws, size_t ws_size,
                              hipStream_t stream)
{
    const float* inputs = (const float*)d_in[0];
    const float* W_ih   = (const float*)d_in[1];
    const float* W_hh   = (const float*)d_in[2];
    const float* b_ih   = (const float*)d_in[3];
    const float* b_hh   = (const float*)d_in[4];
    const float* W_d    = (const float*)d_in[5];
    const float* b_d    = (const float*)d_in[6];
    float* out = (float*)d_out;

    char* ws = (char*)d_ws;
    size_t off = 0;
    auto alloc = [&](size_t bytes) -> char* {
        char* p = ws + off;
        off = (off + bytes + 255) & ~(size_t)255;
        return p;
    };
    bf16_t* B0T   = (bf16_t*)alloc((size_t)NCOLS * 96 * 2);       // linear temp
    bf16_t* B0s   = (bf16_t*)alloc((size_t)NCOLS * 96 * 2);       // frag-swizzled
    bf16_t* BeffT = (bf16_t*)alloc((size_t)3200 * UNITS * 2);     // linear temp
    bf16_t* Bs    = (bf16_t*)alloc((size_t)3200 * UNITS * 2);     // frag-swizzled
    bf16_t* x0s   = (bf16_t*)alloc((size_t)MROWS * 96 * 2);       // frag layout
    bf16_t* h0    = (bf16_t*)alloc((size_t)MROWS * UNITS * 2);    // frag layout
    bf16_t* h1    = (bf16_t*)alloc((size_t)MROWS * UNITS * 2);
    float*  b0r   = (float*)alloc(NCOLS * 4);
    float*  beffr = (float*)alloc(NCOLS * 4);
    int*    ctr   = (int*)alloc(512 * 4);                         // 8 groups x 64 steps

    prep_b0   <<<(NCOLS * 96 + 255) / 256, 256, 0, stream>>>(W_ih, B0T);
    prep_swz  <<<(NCOLS * 96 + 255) / 256, 256, 0, stream>>>(B0T, B0s, 3, 96, NCOLS * 96);
    prep_x0   <<<(MROWS * 96) / 256, 256, 0, stream>>>(inputs, x0s);
    prep_bias <<<(NCOLS + 255) / 256, 256, 0, stream>>>(b_ih, b_hh, W_ih, b_d, b0r, beffr);
    prep_beff2<<<dim3(48, 12), 256, 0, stream>>>(W_hh, W_ih, W_d, BeffT);
    prep_wdt  <<<(128 * UNITS) / 256, 256, 0, stream>>>(W_d, BeffT);
    prep_swz  <<<(3200 * UNITS + 255) / 256, 256, 0, stream>>>(BeffT, Bs, 24, UNITS, 3200 * UNITS);
    zero_ctr  <<<2, 256, 0, stream>>>(ctr);

    // one persistent kernel runs all 64 steps; 200 blocks <= 256 CUs (1 block/CU,
    // LDS-limited at 144 KB), so all blocks are co-resident.
    lstm_persist<<<200, 512, 0, stream>>>(x0s, B0s, Bs, b0r, beffr, b_d,
                                          h0, h1, out, ctr);

    (void)ws_size; (void)in_sizes; (void)n_in; (void)out_size;
}

// Round 5
// 1171.504 us; speedup vs baseline: 1.3471x; 1.3471x over previous
//
#include <hip/hip_runtime.h>
#include <hip/hip_bf16.h>
#include <stdint.h>

typedef __hip_bfloat16 bf16_t;
typedef __attribute__((ext_vector_type(4))) float f32x4;
typedef __attribute__((ext_vector_type(8))) short s16x8;

#define UNITS 768
#define NCOLS 3072        // 4*UNITS (gates, reordered)
#define NPRED 96
#define MROWS 2048

__device__ __forceinline__ float sigf(float x) {
    return __builtin_amdgcn_rcpf(1.f + __expf(-x));
}
__device__ __forceinline__ float tanh_fast(float x) {
    return 1.f - 2.f * __builtin_amdgcn_rcpf(1.f + __expf(2.f * x));
}

// ---------------- prep kernels (once per launch, off critical path) ---------------

// B0T[c][k] = W_ih[g*768+u][k], c-reordered (linear), K=96
__global__ void prep_b0(const float* __restrict__ W_ih, bf16_t* __restrict__ B0T) {
    int idx = blockIdx.x * 256 + threadIdx.x;
    if (idx >= NCOLS * 96) return;
    int c = idx / 96, k = idx % 96;
    int u = ((c >> 6) << 4) + (c & 15);
    int g = (c >> 4) & 3;
    B0T[idx] = (bf16_t)W_ih[(g * UNITS + u) * 96 + k];
}

// x0 in A-fragment layout: elem((mf*3+kf)*512 + l*8 + j) = x[mf*16+(l&15)][kf*32+(l>>4)*8+j]
__global__ void prep_x0(const float* __restrict__ inputs, bf16_t* __restrict__ x0) {
    int idx = blockIdx.x * 256 + threadIdx.x; // 2048*96 = 196608 exactly
    int j = idx & 7;
    int l = (idx >> 3) & 63;
    int fg = idx >> 9;          // mf*3 + kf
    int kf = fg % 3;
    int mf = fg / 3;
    int m = mf * 16 + (l & 15);
    int k = kf * 32 + (l >> 4) * 8 + j;
    x0[idx] = (bf16_t)inputs[(m * 24 + 23) * 96 + k];
}

__global__ void prep_bias(const float* __restrict__ b_ih, const float* __restrict__ b_hh,
                          const float* __restrict__ W_ih, const float* __restrict__ b_d,
                          float* __restrict__ b0_r, float* __restrict__ beff_r) {
    int c = blockIdx.x * 256 + threadIdx.x;
    if (c >= NCOLS) return;
    int u = ((c >> 6) << 4) + (c & 15);
    int g = (c >> 4) & 3;
    int r = g * UNITS + u;
    float v = b_ih[r] + b_hh[r];
    float acc = 0.f;
    for (int j = 0; j < 96; ++j) acc += W_ih[r * 96 + j] * b_d[j];
    b0_r[c] = v;
    beff_r[c] = v + acc;
}

// BeffT[c][k] = W_hh[r(c)][k] + sum_j W_ih[r(c)][j]*W_d[j][k]   (c<3072, LDS-tiled)
__global__ void prep_beff2(const float* __restrict__ W_hh, const float* __restrict__ W_ih,
                           const float* __restrict__ W_d, bf16_t* __restrict__ BeffT) {
    __shared__ float sWih[64][96];
    __shared__ float sWd[96][64];
    const int c0 = blockIdx.x * 64, k0 = blockIdx.y * 64;
    const int tid = threadIdx.x;
    for (int i = tid; i < 64 * 96; i += 256) {
        int cc = i / 96, j = i % 96;
        int c = c0 + cc;
        int u = ((c >> 6) << 4) + (c & 15);
        int g = (c >> 4) & 3;
        sWih[cc][j] = W_ih[(g * UNITS + u) * 96 + j];
    }
    for (int i = tid; i < 96 * 64; i += 256) {
        int j = i / 64, kk = i % 64;
        sWd[j][kk] = W_d[j * UNITS + k0 + kk];
    }
    __syncthreads();
    const int kk = tid & 63;
    const int cc0 = (tid >> 6) * 16;
    for (int cc = cc0; cc < cc0 + 16; ++cc) {
        float acc = 0.f;
#pragma unroll 12
        for (int j = 0; j < 96; ++j) acc += sWih[cc][j] * sWd[j][kk];
        int c = c0 + cc;
        int u = ((c >> 6) << 4) + (c & 15);
        int g = (c >> 4) & 3;
        int r = g * UNITS + u;
        BeffT[(size_t)c * UNITS + k0 + kk] = (bf16_t)(W_hh[(size_t)r * UNITS + k0 + kk] + acc);
    }
}

// rows 3072..3199 of BeffT: W_d rows then zero pad
__global__ void prep_wdt(const float* __restrict__ W_d, bf16_t* __restrict__ BeffT) {
    int idx = blockIdx.x * 256 + threadIdx.x; // 128*768
    int c = idx / UNITS, k = idx % UNITS;
    float v = (c < NPRED) ? W_d[c * UNITS + k] : 0.f;
    BeffT[(size_t)(NCOLS + c) * UNITS + k] = (bf16_t)v;
}

// swizzle linear [c][K] (c pre-reordered) -> B-fragment order:
// elem((((nw*Knk + kf)*4 + f)*64 + l)*8 + j) = src[c][k],
//   c = (nw>>1)*128 + (nw&1)*64 + f*16 + (l&15),  k = kf*32 + (l>>4)*8 + j
__global__ void prep_swz(const bf16_t* __restrict__ src, bf16_t* __restrict__ dst,
                         int Knk, int K, int total) {
    int idx = blockIdx.x * 256 + threadIdx.x;
    if (idx >= total) return;
    int j = idx & 7;
    int l = (idx >> 3) & 63;
    int fg = idx >> 9;
    int f = fg & 3;
    int rest = fg >> 2;
    int kf = rest % Knk;
    int nw = rest / Knk;
    int c = (nw >> 1) * 128 + (nw & 1) * 64 + f * 16 + (l & 15);
    int k = kf * 32 + (l >> 4) * 8 + j;
    dst[idx] = src[(size_t)c * K + k];
}

__global__ void zero_ctr(int* __restrict__ c) {
    int i = blockIdx.x * 256 + threadIdx.x;
    if (i < 768) c[i] = 0;   // [0..511] step ctrs, [512..519] xcd masks, [520..527] setup ctrs
}

// ---------------- persistent kernel: all 64 steps in one launch ---------------
// Geometry: 8 groups x 256 rows; group = 25 blocks x 128 cols (tiles 0..24).
// Block = 256 rows x 128 cols, 8 waves (4 row-slices x 2 col-halves), 512 threads.
// B: frags 0..2 of both 64-col stripes LDS-resident (144 KB); frag 3 streamed
// from global. c-state in registers. 3-slot register pipeline (round-2 proven).
//
// Sync (round-5): per-group runtime check that all 25 blocks share one physical
// XCD (s_getreg HW_REG_XCC_ID — learn_hip m09 verified on MI355X). Fast path
// (local group): local L2 is the coherence point. __syncthreads' vmcnt(0) puts
// h stores in L2; barrier = relaxed AGENT add (L3 RMW) + relaxed AGENT load
// polls (round-2-proven codegen: bypasses vL1/L2, observes remote RMWs) + bare
// `buffer_inv` (sc0=sc1=0 -> vL1-only invalidate; gfx940+ rename of
// buffer_wbinvl1_vol). NO buffer_wbl2, NO L2 invalidation -> h + B-frag3 stay
// L2-resident all 64 steps. Fallback (scattered mapping): byte-identical
// round-2 agent protocol. Correct under any block->XCD mapping.
// All spin failsafes are 1<<20: a protocol bug finishes fast with wrong data
// (diagnosable) instead of timing out the harness.
__global__ __launch_bounds__(512, 2)
void lstm_persist(const bf16_t* __restrict__ x0s,
                  const bf16_t* __restrict__ B0s,
                  const bf16_t* __restrict__ Bs,
                  const float* __restrict__ b0r,
                  const float* __restrict__ beffr,
                  const float* __restrict__ b_d,
                  bf16_t* __restrict__ h0,
                  bf16_t* __restrict__ h1,
                  float* __restrict__ out,
                  int* __restrict__ ctr)
{
    __shared__ __align__(16) bf16_t smem[24 * 6 * 512];   // 73728 elems = 144 KB
    __shared__ int sflag;

    const int tid = threadIdx.x;
    const int wv   = tid >> 6;
    const int lane = tid & 63;
    const int wr = wv >> 1, wc = wv & 1;   // row-slice 0..3, col-half 0..1
    const int l15 = lane & 15, l4 = lane >> 4;

    const int bid  = blockIdx.x;        // 200 blocks
    const int grp  = bid & 7;           // row group 0..7 (256 rows)
    const int tile = bid >> 3;          // 0..24 : 128-col tile
    const bool is_pred = (tile == 24);

    // physical XCD id (scalar, uniform per block) — learn_hip m09 verified
    int xcc;
    asm volatile("s_getreg_b32 %0, hwreg(HW_REG_XCC_ID, 0, 4)" : "=s"(xcc));

    // this wave's global B stripe (64-col stripe 2*tile+wc); frag 3 streamed
    const bf16_t* Bg = Bs + (size_t)(2 * tile + wc) * 49152;

    // ---- stage B frags 0..2 of stripes 2t,2t+1 into LDS (144 KB) ----
    {
        const f32x4* s0 = (const f32x4*)(Bs + (size_t)(2 * tile) * 49152);
        const f32x4* s1 = (const f32x4*)(Bs + (size_t)(2 * tile + 1) * 49152);
        f32x4* dst = (f32x4*)smem;
        for (int i = tid; i < 9216; i += 512) {
            int l  = i & 63;
            int ff = (i >> 6) % 6;          // 0..5
            int kf = i / 384;
            int f  = (ff >= 3) ? ff - 3 : ff;
            const f32x4* src = (ff >= 3) ? s1 : s0;
            dst[i] = src[(kf * 4 + f) * 64 + l];
        }
    }

    // ---- one-time mapping check: is this group entirely on one XCD? ----
    int* smask = ctr + 512;   // per-group XCD bitmaps
    int* sctr  = ctr + 520;   // per-group setup arrival counters
    if (tid == 0) {
        __hip_atomic_fetch_or(smask + grp, 1 << (xcc & 15), __ATOMIC_RELAXED,
                              __HIP_MEMORY_SCOPE_AGENT);
        // RELEASE orders the OR before the arrival increment at the coherent point
        __hip_atomic_fetch_add(sctr + grp, 1, __ATOMIC_RELEASE,
                               __HIP_MEMORY_SCOPE_AGENT);
        int it = 0;
        while (__hip_atomic_load(sctr + grp, __ATOMIC_RELAXED,
                                 __HIP_MEMORY_SCOPE_AGENT) < 25) {
            __builtin_amdgcn_s_sleep(2);
            if (++it > (1 << 20)) break;
        }
        (void)__hip_atomic_load(sctr + grp, __ATOMIC_ACQUIRE,
                                __HIP_MEMORY_SCOPE_AGENT);
        int m = __hip_atomic_load(smask + grp, __ATOMIC_RELAXED,
                                  __HIP_MEMORY_SCOPE_AGENT);
        sflag = (__popc((unsigned)m) == 1) ? 1 : 0;
    }
    __syncthreads();
    const int fast = sflag;

    // ---- per-thread constants ----
    int aoffh[4], aoff0[4];
#pragma unroll
    for (int i = 0; i < 4; ++i) {
        int mf = grp * 16 + wr * 4 + i;     // 16-row fragment index (0..127)
        aoffh[i] = (mf * 24) * 512 + lane * 8;
        aoff0[i] = (mf * 3) * 512 + lane * 8;
    }
    int boff0[4];
#pragma unroll
    for (int f = 0; f < 4; ++f)
        boff0[f] = (((2 * tile + wc) * 12 + f) * 64 + lane) * 8;  // B0s (step 0)

    const int ldsb = wc * 1536 + lane * 8;   // LDS B base (elems); +kt*3072 +f*512
    const int bgof = 1536 + lane * 8;        // global frag 3 base; +kt*2048

    float bi0[4], biS[4];
    if (!is_pred) {
#pragma unroll
        for (int f = 0; f < 4; ++f) {
            int idx = tile * 128 + wc * 64 + f * 16 + l15;
            bi0[f] = b0r[idx];
            biS[f] = beffr[idx];
        }
    } else {
#pragma unroll
        for (int f = 0; f < 4; ++f) {
            int j = wc * 64 + f * 16 + l15;
            biS[f] = (j < NPRED) ? b_d[j] : 0.f;
            bi0[f] = 0.f;
        }
    }

    const int kq = wc * 2 + (l15 >> 3);
    const int jj = l15 & 7;

    f32x4 creg[4];          // persistent cell state for this thread's tile
#pragma unroll
    for (int i = 0; i < 4; ++i) creg[i] = f32x4{0.f, 0.f, 0.f, 0.f};

    int* cbase = ctr + grp * 64;

    f32x4 acc[4][4];

#define ZACC() do {                                                                  \
        _Pragma("unroll") for (int _i = 0; _i < 4; ++_i)                             \
        _Pragma("unroll") for (int _j = 0; _j < 4; ++_j)                             \
            acc[_i][_j] = f32x4{0.f, 0.f, 0.f, 0.f};                                 \
    } while (0)

#define LOADK_H(BUF, KT) do {                                                        \
        _Pragma("unroll")                                                            \
        for (int _i = 0; _i < 4; ++_i)                                               \
            afr[BUF][_i] = *(const s16x8*)(hA + aoffh[_i] + (size_t)(KT) * 512);     \
        _Pragma("unroll")                                                            \
        for (int _f = 0; _f < 3; ++_f)                                               \
            bfr[BUF][_f] = *(const s16x8*)(smem + ldsb + (KT) * 3072 + _f * 512);    \
        bfr[BUF][3] = *(const s16x8*)(Bg + bgof + (size_t)(KT) * 2048);              \
    } while (0)

#define LOADK_0(BUF, KT) do {                                                        \
        _Pragma("unroll")                                                            \
        for (int _i = 0; _i < 4; ++_i)                                               \
            afr[BUF][_i] = *(const s16x8*)(x0s + aoff0[_i] + (size_t)(KT) * 512);    \
        _Pragma("unroll")                                                            \
        for (int _f = 0; _f < 4; ++_f)                                               \
            bfr[BUF][_f] = *(const s16x8*)(B0s + boff0[_f] + (size_t)(KT) * 2048);   \
    } while (0)

#define MF(BUF) do {                                                                 \
        _Pragma("unroll")                                                            \
        for (int _i = 0; _i < 4; ++_i)                                               \
            _Pragma("unroll")                                                        \
            for (int _j = 0; _j < 4; ++_j)                                           \
                acc[_i][_j] = __builtin_amdgcn_mfma_f32_16x16x32_bf16(               \
                    afr[BUF][_i], bfr[BUF][_j], acc[_i][_j], 0, 0, 0);               \
    } while (0)

#define RUN3(NK, LOADK) do {                                                         \
        s16x8 afr[3][4], bfr[3][4];                                                  \
        LOADK(0, 0); LOADK(1, 1);                                                    \
        const int _nk3 = (NK) / 3;                                                   \
        for (int _b3 = 0; _b3 < _nk3; ++_b3) {                                       \
            const int _kt = _b3 * 3;                                                 \
            if (_kt + 2 < (NK)) LOADK(2, _kt + 2);                                   \
            MF(0);                                                                   \
            if (_kt + 3 < (NK)) LOADK(0, _kt + 3);                                   \
            MF(1);                                                                   \
            if (_kt + 4 < (NK)) LOADK(1, _kt + 4);                                   \
            MF(2);                                                                   \
        }                                                                            \
    } while (0)

#define GATE_EPI(HW, BI) do {                                                        \
        _Pragma("unroll")                                                            \
        for (int _i = 0; _i < 4; ++_i) {                                             \
            const int _mf = grp * 16 + wr * 4 + _i;                                  \
            bf16_t* _hb = (HW) + (size_t)(_mf * 24 + tile) * 512;                    \
            _Pragma("unroll")                                                        \
            for (int _r = 0; _r < 4; ++_r) {                                         \
                float _gi = acc[_i][0][_r] + (BI)[0];                                \
                float _gf = acc[_i][1][_r] + (BI)[1];                                \
                float _gg = acc[_i][2][_r] + (BI)[2];                                \
                float _go = acc[_i][3][_r] + (BI)[3];                                \
                float _si = sigf(_gi);                                               \
                float _sf = sigf(_gf);                                               \
                float _tg = tanh_fast(_gg);                                          \
                float _so = sigf(_go);                                               \
                float _cn = _sf * creg[_i][_r] + _si * _tg;                          \
                creg[_i][_r] = _cn;                                                  \
                int _lp = (l4 * 4 + _r) | (kq << 4);                                 \
                _hb[_lp * 8 + jj] = (bf16_t)(_so * tanh_fast(_cn));                  \
            }                                                                        \
        }                                                                            \
    } while (0)

#define PRED_EPI(TCOL) do {                                                          \
        _Pragma("unroll")                                                            \
        for (int _f = 0; _f < 4; ++_f) {                                             \
            int _j = wc * 64 + _f * 16 + l15;                                        \
            if (_j < NPRED) {                                                        \
                _Pragma("unroll")                                                    \
                for (int _i = 0; _i < 4; ++_i)                                       \
                    _Pragma("unroll")                                                \
                    for (int _r = 0; _r < 4; ++_r) {                                 \
                        int _row = grp * 256 + wr * 64 + _i * 16 + l4 * 4 + _r;      \
                        out[((size_t)_row * 64 + (TCOL)) * NPRED + _j] =             \
                            acc[_i][_f][_r] + biS[_f];                               \
                    }                                                                \
            }                                                                        \
        }                                                                            \
    } while (0)

    auto barrier_step = [&](int s) {
        __syncthreads();          // vmcnt(0): all waves' h stores are in local L2
        if (fast) {
            // XCD-local group: no cache flush/inv of L2 at all.
            if (tid == 0) {
                __hip_atomic_fetch_add(cbase + s, 1, __ATOMIC_RELAXED,
                                       __HIP_MEMORY_SCOPE_AGENT);
                int it = 0;
                while (__hip_atomic_load(cbase + s, __ATOMIC_RELAXED,
                                         __HIP_MEMORY_SCOPE_AGENT) < 25) {
                    __builtin_amdgcn_s_sleep(2);
                    if (++it > (1 << 20)) break;   // failsafe: finish, don't hang
                }
            }
            __syncthreads();
            // drop stale per-CU vL1 lines (h of prior steps); L2 holds fresh h
            asm volatile("buffer_inv" ::: "memory");
            asm volatile("s_waitcnt vmcnt(0)" ::: "memory");
        } else {
            // round-2-proven agent protocol (scattered-mapping fallback)
            if (tid == 0) {
                if (is_pred) {
                    __hip_atomic_fetch_add(cbase + s, 1, __ATOMIC_RELAXED,
                                           __HIP_MEMORY_SCOPE_AGENT);
                } else {
                    __hip_atomic_fetch_add(cbase + s, 1, __ATOMIC_RELEASE,
                                           __HIP_MEMORY_SCOPE_AGENT);
                }
                int it = 0;
                while (__hip_atomic_load(cbase + s, __ATOMIC_RELAXED,
                                         __HIP_MEMORY_SCOPE_AGENT) < 25) {
                    __builtin_amdgcn_s_sleep(4);
                    if (++it > (1 << 20)) break;
                }
                (void)__hip_atomic_load(cbase + s, __ATOMIC_ACQUIRE,
                                        __HIP_MEMORY_SCOPE_AGENT);
            }
            __syncthreads();
        }
    };

    // ---- step 0: gates from x0 (Knk=3), c=h=0; pred idle ----
    if (!is_pred) {
        ZACC();
        RUN3(3, LOADK_0);
        GATE_EPI(h1, bi0);
    }
    barrier_step(0);

    // ---- steps 1..63 ----
    for (int s = 1; s < 64; ++s) {
        const bf16_t* hA = (s & 1) ? h1 : h0;
        ZACC();
        RUN3(24, LOADK_H);
        if (!is_pred) {
            bf16_t* hW = ((s + 1) & 1) ? h1 : h0;
            GATE_EPI(hW, biS);
        } else {
            PRED_EPI(s - 1);
        }
        barrier_step(s);
    }

    // ---- step 64: final prediction from h_64 (in h0) ----
    if (is_pred) {
        const bf16_t* hA = h0;
        ZACC();
        RUN3(24, LOADK_H);
        PRED_EPI(63);
    }

#undef ZACC
#undef LOADK_H
#undef LOADK_0
#undef MF
#undef RUN3
#undef GATE_EPI
#undef PRED_EPI
}

extern "C" void kernel_launch(void* const* d_in, const int* in_sizes, int n_in,
                              void* d_out, int out_size, void* d_ws, size_t ws_size,
                              hipStream_t stream)
{
    const float* inputs = (const float*)d_in[0];
    const float* W_ih   = (const float*)d_in[1];
    const float* W_hh   = (const float*)d_in[2];
    const float* b_ih   = (const float*)d_in[3];
    const float* b_hh   = (const float*)d_in[4];
    const float* W_d    = (const float*)d_in[5];
    const float* b_d    = (const float*)d_in[6];
    float* out = (float*)d_out;

    char* ws = (char*)d_ws;
    size_t off = 0;
    auto alloc = [&](size_t bytes) -> char* {
        char* p = ws + off;
        off = (off + bytes + 255) & ~(size_t)255;
        return p;
    };
    bf16_t* B0T   = (bf16_t*)alloc((size_t)NCOLS * 96 * 2);       // linear temp
    bf16_t* B0s   = (bf16_t*)alloc((size_t)NCOLS * 96 * 2);       // frag-swizzled
    bf16_t* BeffT = (bf16_t*)alloc((size_t)3200 * UNITS * 2);     // linear temp
    bf16_t* Bs    = (bf16_t*)alloc((size_t)3200 * UNITS * 2);     // frag-swizzled
    bf16_t* x0s   = (bf16_t*)alloc((size_t)MROWS * 96 * 2);       // frag layout
    bf16_t* h0    = (bf16_t*)alloc((size_t)MROWS * UNITS * 2);    // frag layout
    bf16_t* h1    = (bf16_t*)alloc((size_t)MROWS * UNITS * 2);
    float*  b0r   = (float*)alloc(NCOLS * 4);
    float*  beffr = (float*)alloc(NCOLS * 4);
    int*    ctr   = (int*)alloc(768 * 4);  // [0..511] step ctrs, [512..527] setup

    prep_b0   <<<(NCOLS * 96 + 255) / 256, 256, 0, stream>>>(W_ih, B0T);
    prep_swz  <<<(NCOLS * 96 + 255) / 256, 256, 0, stream>>>(B0T, B0s, 3, 96, NCOLS * 96);
    prep_x0   <<<(MROWS * 96) / 256, 256, 0, stream>>>(inputs, x0s);
    prep_bias <<<(NCOLS + 255) / 256, 256, 0, stream>>>(b_ih, b_hh, W_ih, b_d, b0r, beffr);
    prep_beff2<<<dim3(48, 12), 256, 0, stream>>>(W_hh, W_ih, W_d, BeffT);
    prep_wdt  <<<(128 * UNITS) / 256, 256, 0, stream>>>(W_d, BeffT);
    prep_swz  <<<(3200 * UNITS + 255) / 256, 256, 0, stream>>>(BeffT, Bs, 24, UNITS, 3200 * UNITS);
    zero_ctr  <<<3, 256, 0, stream>>>(ctr);

    // one persistent kernel runs all 64 steps; 200 blocks <= 256 CUs (1 block/CU,
    // LDS-limited at 144 KB), so all blocks are co-resident.
    lstm_persist<<<200, 512, 0, stream>>>(x0s, B0s, Bs, b0r, beffr, b_d,
                                          h0, h1, out, ctr);

    (void)ws_size; (void)in_sizes; (void)n_in; (void)out_size;
}

// Round 6
// 1167.058 us; speedup vs baseline: 1.3522x; 1.0038x over previous
//
#include <hip/hip_runtime.h>
#include <hip/hip_bf16.h>
#include <stdint.h>

typedef __hip_bfloat16 bf16_t;
typedef __attribute__((ext_vector_type(4))) float f32x4;
typedef __attribute__((ext_vector_type(8))) short s16x8;

#define UNITS 768
#define NCOLS 3072        // 4*UNITS (gates, reordered)
#define NPRED 96
#define MROWS 2048

__device__ __forceinline__ float sigf(float x) {
    return __builtin_amdgcn_rcpf(1.f + __expf(-x));
}
__device__ __forceinline__ float tanh_fast(float x) {
    return 1.f - 2.f * __builtin_amdgcn_rcpf(1.f + __expf(2.f * x));
}

// ---------------- prep kernels (once per launch, off critical path) ---------------

// B0T[c][k] = W_ih[g*768+u][k], c-reordered (linear), K=96
__global__ void prep_b0(const float* __restrict__ W_ih, bf16_t* __restrict__ B0T) {
    int idx = blockIdx.x * 256 + threadIdx.x;
    if (idx >= NCOLS * 96) return;
    int c = idx / 96, k = idx % 96;
    int u = ((c >> 6) << 4) + (c & 15);
    int g = (c >> 4) & 3;
    B0T[idx] = (bf16_t)W_ih[(g * UNITS + u) * 96 + k];
}

// x0 in A-fragment layout: elem((mf*3+kf)*512 + l*8 + j) = x[mf*16+(l&15)][kf*32+(l>>4)*8+j]
__global__ void prep_x0(const float* __restrict__ inputs, bf16_t* __restrict__ x0) {
    int idx = blockIdx.x * 256 + threadIdx.x; // 2048*96 = 196608 exactly
    int j = idx & 7;
    int l = (idx >> 3) & 63;
    int fg = idx >> 9;          // mf*3 + kf
    int kf = fg % 3;
    int mf = fg / 3;
    int m = mf * 16 + (l & 15);
    int k = kf * 32 + (l >> 4) * 8 + j;
    x0[idx] = (bf16_t)inputs[(m * 24 + 23) * 96 + k];
}

__global__ void prep_bias(const float* __restrict__ b_ih, const float* __restrict__ b_hh,
                          const float* __restrict__ W_ih, const float* __restrict__ b_d,
                          float* __restrict__ b0_r, float* __restrict__ beff_r) {
    int c = blockIdx.x * 256 + threadIdx.x;
    if (c >= NCOLS) return;
    int u = ((c >> 6) << 4) + (c & 15);
    int g = (c >> 4) & 3;
    int r = g * UNITS + u;
    float v = b_ih[r] + b_hh[r];
    float acc = 0.f;
    for (int j = 0; j < 96; ++j) acc += W_ih[r * 96 + j] * b_d[j];
    b0_r[c] = v;
    beff_r[c] = v + acc;
}

// BeffT[c][k] = W_hh[r(c)][k] + sum_j W_ih[r(c)][j]*W_d[j][k]   (c<3072, LDS-tiled)
__global__ void prep_beff2(const float* __restrict__ W_hh, const float* __restrict__ W_ih,
                           const float* __restrict__ W_d, bf16_t* __restrict__ BeffT) {
    __shared__ float sWih[64][96];
    __shared__ float sWd[96][64];
    const int c0 = blockIdx.x * 64, k0 = blockIdx.y * 64;
    const int tid = threadIdx.x;
    for (int i = tid; i < 64 * 96; i += 256) {
        int cc = i / 96, j = i % 96;
        int c = c0 + cc;
        int u = ((c >> 6) << 4) + (c & 15);
        int g = (c >> 4) & 3;
        sWih[cc][j] = W_ih[(g * UNITS + u) * 96 + j];
    }
    for (int i = tid; i < 96 * 64; i += 256) {
        int j = i / 64, kk = i % 64;
        sWd[j][kk] = W_d[j * UNITS + k0 + kk];
    }
    __syncthreads();
    const int kk = tid & 63;
    const int cc0 = (tid >> 6) * 16;
    for (int cc = cc0; cc < cc0 + 16; ++cc) {
        float acc = 0.f;
#pragma unroll 12
        for (int j = 0; j < 96; ++j) acc += sWih[cc][j] * sWd[j][kk];
        int c = c0 + cc;
        int u = ((c >> 6) << 4) + (c & 15);
        int g = (c >> 4) & 3;
        int r = g * UNITS + u;
        BeffT[(size_t)c * UNITS + k0 + kk] = (bf16_t)(W_hh[(size_t)r * UNITS + k0 + kk] + acc);
    }
}

// rows 3072..3199 of BeffT: W_d rows then zero pad
__global__ void prep_wdt(const float* __restrict__ W_d, bf16_t* __restrict__ BeffT) {
    int idx = blockIdx.x * 256 + threadIdx.x; // 128*768
    int c = idx / UNITS, k = idx % UNITS;
    float v = (c < NPRED) ? W_d[c * UNITS + k] : 0.f;
    BeffT[(size_t)(NCOLS + c) * UNITS + k] = (bf16_t)v;
}

// swizzle linear [c][K] (c pre-reordered) -> B-fragment order:
// elem((((nw*Knk + kf)*4 + f)*64 + l)*8 + j) = src[c][k],
//   c = (nw>>1)*128 + (nw&1)*64 + f*16 + (l&15),  k = kf*32 + (l>>4)*8 + j
__global__ void prep_swz(const bf16_t* __restrict__ src, bf16_t* __restrict__ dst,
                         int Knk, int K, int total) {
    int idx = blockIdx.x * 256 + threadIdx.x;
    if (idx >= total) return;
    int j = idx & 7;
    int l = (idx >> 3) & 63;
    int fg = idx >> 9;
    int f = fg & 3;
    int rest = fg >> 2;
    int kf = rest % Knk;
    int nw = rest / Knk;
    int c = (nw >> 1) * 128 + (nw & 1) * 64 + f * 16 + (l & 15);
    int k = kf * 32 + (l >> 4) * 8 + j;
    dst[idx] = src[(size_t)c * K + k];
}

__global__ void zero_ctr(int* __restrict__ c) {
    int i = blockIdx.x * 256 + threadIdx.x;
    if (i < 768) c[i] = 0;   // [0..511] step ctrs, [512..519] xcd masks, [520..527] setup ctrs
}

// ---------------- persistent kernel: all 64 steps in one launch ---------------
// Geometry: 8 groups x 256 rows; group = 25 blocks x 128 cols (tiles 0..24).
// Block = 256 rows x 128 cols, 8 waves (4 row-slices x 2 col-halves), 512 threads.
// B: frags 0..2 of both 64-col stripes LDS-resident (144 KB); frag 3 streamed
// from global. c-state in registers.
//
// Round-6 change: LDS (144 KB) pins occupancy at 1 block/CU = 2 waves/EU, but
// the allocator was targeting 4 waves/EU and capped VGPR at 128 -> the register
// pipeline silently collapsed to ~1 slot and every kt exposed L2 latency.
// amdgpu_waves_per_eu(2,2) declares the true occupancy -> 256-VGPR budget, and
// RUN4 (4-slot, 3-deep prefetch: 128 frag + 64 acc + 16 creg + ~30 misc ~= 238)
// actually fits. Sync protocol is byte-identical to round 5 (proven PASS):
// runtime single-XCD check per group; fast path = relaxed agent add + relaxed
// agent polls + bare vL1-only buffer_inv (no wbl2, no L2 inv); fallback =
// round-2 agent protocol. Correct under any block->XCD mapping.
__global__ __attribute__((amdgpu_flat_work_group_size(512, 512),
                          amdgpu_waves_per_eu(2, 2)))
void lstm_persist(const bf16_t* __restrict__ x0s,
                  const bf16_t* __restrict__ B0s,
                  const bf16_t* __restrict__ Bs,
                  const float* __restrict__ b0r,
                  const float* __restrict__ beffr,
                  const float* __restrict__ b_d,
                  bf16_t* __restrict__ h0,
                  bf16_t* __restrict__ h1,
                  float* __restrict__ out,
                  int* __restrict__ ctr)
{
    __shared__ __align__(16) bf16_t smem[24 * 6 * 512];   // 73728 elems = 144 KB
    __shared__ int sflag;

    const int tid = threadIdx.x;
    const int wv   = tid >> 6;
    const int lane = tid & 63;
    const int wr = wv >> 1, wc = wv & 1;   // row-slice 0..3, col-half 0..1
    const int l15 = lane & 15, l4 = lane >> 4;

    const int bid  = blockIdx.x;        // 200 blocks
    const int grp  = bid & 7;           // row group 0..7 (256 rows)
    const int tile = bid >> 3;          // 0..24 : 128-col tile
    const bool is_pred = (tile == 24);

    // physical XCD id (scalar, uniform per block) — learn_hip m09 verified
    int xcc;
    asm volatile("s_getreg_b32 %0, hwreg(HW_REG_XCC_ID, 0, 4)" : "=s"(xcc));

    // this wave's global B stripe (64-col stripe 2*tile+wc); frag 3 streamed
    const bf16_t* Bg = Bs + (size_t)(2 * tile + wc) * 49152;

    // ---- stage B frags 0..2 of stripes 2t,2t+1 into LDS (144 KB) ----
    {
        const f32x4* s0 = (const f32x4*)(Bs + (size_t)(2 * tile) * 49152);
        const f32x4* s1 = (const f32x4*)(Bs + (size_t)(2 * tile + 1) * 49152);
        f32x4* dst = (f32x4*)smem;
        for (int i = tid; i < 9216; i += 512) {
            int l  = i & 63;
            int ff = (i >> 6) % 6;          // 0..5
            int kf = i / 384;
            int f  = (ff >= 3) ? ff - 3 : ff;
            const f32x4* src = (ff >= 3) ? s1 : s0;
            dst[i] = src[(kf * 4 + f) * 64 + l];
        }
    }

    // ---- one-time mapping check: is this group entirely on one XCD? ----
    int* smask = ctr + 512;   // per-group XCD bitmaps
    int* sctr  = ctr + 520;   // per-group setup arrival counters
    if (tid == 0) {
        __hip_atomic_fetch_or(smask + grp, 1 << (xcc & 15), __ATOMIC_RELAXED,
                              __HIP_MEMORY_SCOPE_AGENT);
        // RELEASE orders the OR before the arrival increment at the coherent point
        __hip_atomic_fetch_add(sctr + grp, 1, __ATOMIC_RELEASE,
                               __HIP_MEMORY_SCOPE_AGENT);
        int it = 0;
        while (__hip_atomic_load(sctr + grp, __ATOMIC_RELAXED,
                                 __HIP_MEMORY_SCOPE_AGENT) < 25) {
            __builtin_amdgcn_s_sleep(2);
            if (++it > (1 << 20)) break;
        }
        (void)__hip_atomic_load(sctr + grp, __ATOMIC_ACQUIRE,
                                __HIP_MEMORY_SCOPE_AGENT);
        int m = __hip_atomic_load(smask + grp, __ATOMIC_RELAXED,
                                  __HIP_MEMORY_SCOPE_AGENT);
        sflag = (__popc((unsigned)m) == 1) ? 1 : 0;
    }
    __syncthreads();
    const int fast = sflag;

    // ---- per-thread constants ----
    int aoffh[4], aoff0[4];
#pragma unroll
    for (int i = 0; i < 4; ++i) {
        int mf = grp * 16 + wr * 4 + i;     // 16-row fragment index (0..127)
        aoffh[i] = (mf * 24) * 512 + lane * 8;
        aoff0[i] = (mf * 3) * 512 + lane * 8;
    }
    int boff0[4];
#pragma unroll
    for (int f = 0; f < 4; ++f)
        boff0[f] = (((2 * tile + wc) * 12 + f) * 64 + lane) * 8;  // B0s (step 0)

    const int ldsb = wc * 1536 + lane * 8;   // LDS B base (elems); +kt*3072 +f*512
    const int bgof = 1536 + lane * 8;        // global frag 3 base; +kt*2048

    float bi0[4], biS[4];
    if (!is_pred) {
#pragma unroll
        for (int f = 0; f < 4; ++f) {
            int idx = tile * 128 + wc * 64 + f * 16 + l15;
            bi0[f] = b0r[idx];
            biS[f] = beffr[idx];
        }
    } else {
#pragma unroll
        for (int f = 0; f < 4; ++f) {
            int j = wc * 64 + f * 16 + l15;
            biS[f] = (j < NPRED) ? b_d[j] : 0.f;
            bi0[f] = 0.f;
        }
    }

    const int kq = wc * 2 + (l15 >> 3);
    const int jj = l15 & 7;

    f32x4 creg[4];          // persistent cell state for this thread's tile
#pragma unroll
    for (int i = 0; i < 4; ++i) creg[i] = f32x4{0.f, 0.f, 0.f, 0.f};

    int* cbase = ctr + grp * 64;

    f32x4 acc[4][4];

#define ZACC() do {                                                                  \
        _Pragma("unroll") for (int _i = 0; _i < 4; ++_i)                             \
        _Pragma("unroll") for (int _j = 0; _j < 4; ++_j)                             \
            acc[_i][_j] = f32x4{0.f, 0.f, 0.f, 0.f};                                 \
    } while (0)

#define LOADK_H(BUF, KT) do {                                                        \
        _Pragma("unroll")                                                            \
        for (int _i = 0; _i < 4; ++_i)                                               \
            afr[BUF][_i] = *(const s16x8*)(hA + aoffh[_i] + (size_t)(KT) * 512);     \
        _Pragma("unroll")                                                            \
        for (int _f = 0; _f < 3; ++_f)                                               \
            bfr[BUF][_f] = *(const s16x8*)(smem + ldsb + (KT) * 3072 + _f * 512);    \
        bfr[BUF][3] = *(const s16x8*)(Bg + bgof + (size_t)(KT) * 2048);              \
    } while (0)

#define LOADK_0(BUF, KT) do {                                                        \
        _Pragma("unroll")                                                            \
        for (int _i = 0; _i < 4; ++_i)                                               \
            afr[BUF][_i] = *(const s16x8*)(x0s + aoff0[_i] + (size_t)(KT) * 512);    \
        _Pragma("unroll")                                                            \
        for (int _f = 0; _f < 4; ++_f)                                               \
            bfr[BUF][_f] = *(const s16x8*)(B0s + boff0[_f] + (size_t)(KT) * 2048);   \
    } while (0)

#define MF(BUF) do {                                                                 \
        _Pragma("unroll")                                                            \
        for (int _i = 0; _i < 4; ++_i)                                               \
            _Pragma("unroll")                                                        \
            for (int _j = 0; _j < 4; ++_j)                                           \
                acc[_i][_j] = __builtin_amdgcn_mfma_f32_16x16x32_bf16(               \
                    afr[BUF][_i], bfr[BUF][_j], acc[_i][_j], 0, 0, 0);               \
    } while (0)

// 4-slot register pipeline, 3-deep prefetch (needs the 256-VGPR budget that
// amdgpu_waves_per_eu(2,2) unlocks; at 128 VGPR this collapses — round 3/5)
#define RUN4(NK, LOADK) do {                                                         \
        s16x8 afr[4][4], bfr[4][4];                                                  \
        LOADK(0, 0);                                                                 \
        if (1 < (NK)) LOADK(1, 1);                                                   \
        if (2 < (NK)) LOADK(2, 2);                                                   \
        _Pragma("unroll")                                                            \
        for (int _kt = 0; _kt < (NK); _kt += 4) {                                    \
            if (_kt + 3 < (NK)) LOADK(3, _kt + 3);                                   \
            MF(0);                                                                   \
            if (_kt + 4 < (NK)) LOADK(0, _kt + 4);                                   \
            if (_kt + 1 < (NK)) MF(1);                                               \
            if (_kt + 5 < (NK)) LOADK(1, _kt + 5);                                   \
            if (_kt + 2 < (NK)) MF(2);                                               \
            if (_kt + 6 < (NK)) LOADK(2, _kt + 6);                                   \
            if (_kt + 3 < (NK)) MF(3);                                               \
        }                                                                            \
    } while (0)

#define GATE_EPI(HW, BI) do {                                                        \
        _Pragma("unroll")                                                            \
        for (int _i = 0; _i < 4; ++_i) {                                             \
            const int _mf = grp * 16 + wr * 4 + _i;                                  \
            bf16_t* _hb = (HW) + (size_t)(_mf * 24 + tile) * 512;                    \
            _Pragma("unroll")                                                        \
            for (int _r = 0; _r < 4; ++_r) {                                         \
                float _gi = acc[_i][0][_r] + (BI)[0];                                \
                float _gf = acc[_i][1][_r] + (BI)[1];                                \
                float _gg = acc[_i][2][_r] + (BI)[2];                                \
                float _go = acc[_i][3][_r] + (BI)[3];                                \
                float _si = sigf(_gi);                                               \
                float _sf = sigf(_gf);                                               \
                float _tg = tanh_fast(_gg);                                          \
                float _so = sigf(_go);                                               \
                float _cn = _sf * creg[_i][_r] + _si * _tg;                          \
                creg[_i][_r] = _cn;                                                  \
                int _lp = (l4 * 4 + _r) | (kq << 4);                                 \
                _hb[_lp * 8 + jj] = (bf16_t)(_so * tanh_fast(_cn));                  \
            }                                                                        \
        }                                                                            \
    } while (0)

#define PRED_EPI(TCOL) do {                                                          \
        _Pragma("unroll")                                                            \
        for (int _f = 0; _f < 4; ++_f) {                                             \
            int _j = wc * 64 + _f * 16 + l15;                                        \
            if (_j < NPRED) {                                                        \
                _Pragma("unroll")                                                    \
                for (int _i = 0; _i < 4; ++_i)                                       \
                    _Pragma("unroll")                                                \
                    for (int _r = 0; _r < 4; ++_r) {                                 \
                        int _row = grp * 256 + wr * 64 + _i * 16 + l4 * 4 + _r;      \
                        out[((size_t)_row * 64 + (TCOL)) * NPRED + _j] =             \
                            acc[_i][_f][_r] + biS[_f];                               \
                    }                                                                \
            }                                                                        \
        }                                                                            \
    } while (0)

    auto barrier_step = [&](int s) {
        __syncthreads();          // vmcnt(0): all waves' h stores are in local L2
        if (fast) {
            // XCD-local group: no cache flush/inv of L2 at all.
            if (tid == 0) {
                __hip_atomic_fetch_add(cbase + s, 1, __ATOMIC_RELAXED,
                                       __HIP_MEMORY_SCOPE_AGENT);
                int it = 0;
                while (__hip_atomic_load(cbase + s, __ATOMIC_RELAXED,
                                         __HIP_MEMORY_SCOPE_AGENT) < 25) {
                    __builtin_amdgcn_s_sleep(1);
                    if (++it > (1 << 20)) break;   // failsafe: finish, don't hang
                }
            }
            __syncthreads();
            // drop stale per-CU vL1 lines (h of prior steps); L2 holds fresh h
            asm volatile("buffer_inv" ::: "memory");
            asm volatile("s_waitcnt vmcnt(0)" ::: "memory");
        } else {
            // round-2-proven agent protocol (scattered-mapping fallback)
            if (tid == 0) {
                if (is_pred) {
                    __hip_atomic_fetch_add(cbase + s, 1, __ATOMIC_RELAXED,
                                           __HIP_MEMORY_SCOPE_AGENT);
                } else {
                    __hip_atomic_fetch_add(cbase + s, 1, __ATOMIC_RELEASE,
                                           __HIP_MEMORY_SCOPE_AGENT);
                }
                int it = 0;
                while (__hip_atomic_load(cbase + s, __ATOMIC_RELAXED,
                                         __HIP_MEMORY_SCOPE_AGENT) < 25) {
                    __builtin_amdgcn_s_sleep(4);
                    if (++it > (1 << 20)) break;
                }
                (void)__hip_atomic_load(cbase + s, __ATOMIC_ACQUIRE,
                                        __HIP_MEMORY_SCOPE_AGENT);
            }
            __syncthreads();
        }
    };

    // ---- step 0: gates from x0 (Knk=3), c=h=0; pred idle ----
    if (!is_pred) {
        ZACC();
        RUN4(3, LOADK_0);
        GATE_EPI(h1, bi0);
    }
    barrier_step(0);

    // ---- steps 1..63 ----
    for (int s = 1; s < 64; ++s) {
        const bf16_t* hA = (s & 1) ? h1 : h0;
        ZACC();
        RUN4(24, LOADK_H);
        if (!is_pred) {
            bf16_t* hW = ((s + 1) & 1) ? h1 : h0;
            GATE_EPI(hW, biS);
        } else {
            PRED_EPI(s - 1);
        }
        barrier_step(s);
    }

    // ---- step 64: final prediction from h_64 (in h0) ----
    if (is_pred) {
        const bf16_t* hA = h0;
        ZACC();
        RUN4(24, LOADK_H);
        PRED_EPI(63);
    }

#undef ZACC
#undef LOADK_H
#undef LOADK_0
#undef MF
#undef RUN4
#undef GATE_EPI
#undef PRED_EPI
}

extern "C" void kernel_launch(void* const* d_in, const int* in_sizes, int n_in,
                              void* d_out, int out_size, void* d_ws, size_t ws_size,
                              hipStream_t stream)
{
    const float* inputs = (const float*)d_in[0];
    const float* W_ih   = (const float*)d_in[1];
    const float* W_hh   = (const float*)d_in[2];
    const float* b_ih   = (const float*)d_in[3];
    const float* b_hh   = (const float*)d_in[4];
    const float* W_d    = (const float*)d_in[5];
    const float* b_d    = (const float*)d_in[6];
    float* out = (float*)d_out;

    char* ws = (char*)d_ws;
    size_t off = 0;
    auto alloc = [&](size_t bytes) -> char* {
        char* p = ws + off;
        off = (off + bytes + 255) & ~(size_t)255;
        return p;
    };
    bf16_t* B0T   = (bf16_t*)alloc((size_t)NCOLS * 96 * 2);       // linear temp
    bf16_t* B0s   = (bf16_t*)alloc((size_t)NCOLS * 96 * 2);       // frag-swizzled
    bf16_t* BeffT = (bf16_t*)alloc((size_t)3200 * UNITS * 2);     // linear temp
    bf16_t* Bs    = (bf16_t*)alloc((size_t)3200 * UNITS * 2);     // frag-swizzled
    bf16_t* x0s   = (bf16_t*)alloc((size_t)MROWS * 96 * 2);       // frag layout
    bf16_t* h0    = (bf16_t*)alloc((size_t)MROWS * UNITS * 2);    // frag layout
    bf16_t* h1    = (bf16_t*)alloc((size_t)MROWS * UNITS * 2);
    float*  b0r   = (float*)alloc(NCOLS * 4);
    float*  beffr = (float*)alloc(NCOLS * 4);
    int*    ctr   = (int*)alloc(768 * 4);  // [0..511] step ctrs, [512..527] setup

    prep_b0   <<<(NCOLS * 96 + 255) / 256, 256, 0, stream>>>(W_ih, B0T);
    prep_swz  <<<(NCOLS * 96 + 255) / 256, 256, 0, stream>>>(B0T, B0s, 3, 96, NCOLS * 96);
    prep_x0   <<<(MROWS * 96) / 256, 256, 0, stream>>>(inputs, x0s);
    prep_bias <<<(NCOLS + 255) / 256, 256, 0, stream>>>(b_ih, b_hh, W_ih, b_d, b0r, beffr);
    prep_beff2<<<dim3(48, 12), 256, 0, stream>>>(W_hh, W_ih, W_d, BeffT);
    prep_wdt  <<<(128 * UNITS) / 256, 256, 0, stream>>>(W_d, BeffT);
    prep_swz  <<<(3200 * UNITS + 255) / 256, 256, 0, stream>>>(BeffT, Bs, 24, UNITS, 3200 * UNITS);
    zero_ctr  <<<3, 256, 0, stream>>>(ctr);

    // one persistent kernel runs all 64 steps; 200 blocks <= 256 CUs (1 block/CU,
    // LDS-limited at 144 KB), so all blocks are co-resident.
    lstm_persist<<<200, 512, 0, stream>>>(x0s, B0s, Bs, b0r, beffr, b_d,
                                          h0, h1, out, ctr);

    (void)ws_size; (void)in_sizes; (void)n_in; (void)out_size;
}